// Round 8
// baseline (233.590 us; speedup 1.0000x reference)
//
#include <hip/hip_runtime.h>

// SparseMLP (grouped GEMM MoE): out = gelu_tanh(x @ w1^T) @ w2, per expert.
// E=64, CAP=64, H=1024, F=2048, fp32 in/out. HBM-bound: ~1.07 GB moved,
// roofline ~165-180us at the 6.3-6.9 TB/s achievable ceiling.
// R8: revert R7's 3-deep reg prefetch (VGPR regression). Pass 1 restructured
// to global_load_lds staging: fp32 tiles at BK=32, THREE LDS buffers,
// counted s_waitcnt vmcnt(3) at the barrier (tile k+2 stays in flight ->
// ~2 iterations of latency cover), zero staging registers/VALU. LDS linear
// dest + inverse-swizzled global SOURCE + swizzled ds_read (rule 21; XOR of
// chunk index with row&7). fp32->bf16 at fragment read. Pass 2 = R6.

typedef __attribute__((ext_vector_type(8))) short short8;    // 8 bf16 = 4 VGPR
typedef __attribute__((ext_vector_type(4))) float f32x4;     // MFMA acc / ld
typedef __attribute__((ext_vector_type(8))) unsigned short ushort8;

#define NE   64
#define CAPT 64
#define HD   1024
#define FD   2048

// fp32 -> bf16 round-to-nearest-even
__device__ __forceinline__ unsigned short f2bf(float f) {
  union { float f; unsigned u; } v; v.f = f;
  unsigned r = v.u + 0x7FFFu + ((v.u >> 16) & 1u);
  return (unsigned short)(r >> 16);
}

// gelu_tanh(v) = v * sigmoid(2*0.79788456*(v + 0.044715 v^3))  (exact rewrite)
__device__ __forceinline__ float gelu_t(float v) {
  float u = 1.5957691216057308f * (v + 0.044715f * v * v * v);
  return v / (1.0f + __expf(-u));
}

// Byte offset inside a [rows][64]-bf16 LDS tile (row stride 128B) with the
// XOR swizzle that makes column-slice ds_read_b128 bank-conflict-free (G4).
// (pass-2 staging path)
__device__ __forceinline__ int swz(int row, int kbyte) {
  return row * 128 + (kbyte ^ ((row & 7) << 4));
}

__device__ __forceinline__ void cvt_wr4(unsigned char* dst, f32x4 v) {
  uint2 p;
  p.x = (unsigned)f2bf(v.x) | ((unsigned)f2bf(v.y) << 16);
  p.y = (unsigned)f2bf(v.z) | ((unsigned)f2bf(v.w) << 16);
  *(uint2*)dst = p;   // ds_write_b64
}

// Raw barrier with LDS-only drain (T4), pass-2 loop.
__device__ __forceinline__ void tile_barrier() {
  asm volatile("s_waitcnt lgkmcnt(0)" ::: "memory");
  __builtin_amdgcn_s_barrier();
  __builtin_amdgcn_sched_barrier(0);
}

// Bijective XCD swizzle (T1): same-expert blocks share an L2.
__device__ __forceinline__ int xcd_swz(int bid, int grid) {
  return (bid & 7) * (grid >> 3) + (bid >> 3);
}

// global -> LDS async copy, 16B per lane. Dest = wave-uniform base + lane*16.
typedef __attribute__((address_space(1))) const void gvoid_t;
typedef __attribute__((address_space(3))) void lvoid_t;
__device__ __forceinline__ void gl16(const float* g, void* l) {
  __builtin_amdgcn_global_load_lds((gvoid_t*)g, (lvoid_t*)l, 16, 0, 0);
}
__device__ __forceinline__ void gl16nt(const float* g, void* l) {
  __builtin_amdgcn_global_load_lds((gvoid_t*)g, (lvoid_t*)l, 16, 0, 2); // slc/nt
}

// ---------------------------------------------------------------- pass 1 ---
// C1[64,2048] = x_e[64,1024] @ w1_e[2048,1024]^T  (NT: both K-contiguous)
// grid = E*(F/128); tile BM=64 BN=128 BK=32(fp32 in LDS); 8 waves (2x4),
// wave tile 32x32. 3 LDS buffers, global_load_lds, counted vmcnt(3).
__global__ __launch_bounds__(512, 4)
void moe_pass1(const float* __restrict__ x, const float* __restrict__ w1,
               unsigned short* __restrict__ hb) {
  __shared__ __align__(16) float sA[3][64 * 32];    // 3 x 8 KB
  __shared__ __align__(16) float sB[3][128 * 32];   // 3 x 16 KB
  const int bid = xcd_swz(blockIdx.x, NE * 16);
  const int e = bid >> 4, nb = bid & 15;
  const int t = threadIdx.x, lane = t & 63, wid = t >> 6;
  const int wm = wid >> 2, wn = wid & 3;
  const int lr = lane & 15, kg = lane >> 4;

  const float* xg  = x  + (size_t)e * CAPT * HD;
  const float* w1g = w1 + ((size_t)e * FD + (size_t)nb * 128) * HD;

  f32x4 acc[2][2] = {};

  // Staging geometry: tile rows of 32 fp32 = 8 chunks of 16B. Thread t owns
  // A-chunk t (rows 0..63) and B-chunks t, t+512 (rows 0..127). LDS is
  // LINEAR in chunk order; the global source takes the inverse swizzle
  // (chunk ^ (row&7)) so that swizzled ds_reads see the right data.
  const int ar  = t >> 3;
  const int ao  = ar * HD + (((t & 7) ^ (ar & 7)) << 2);
  const int b1r = t >> 3;
  const int bo1 = b1r * HD + (((t & 7) ^ (b1r & 7)) << 2);
  const int b2r = 64 + (t >> 3);
  const int bo2 = b2r * HD + (((t & 7) ^ (b2r & 7)) << 2);
  const int lbase = wid * 1024;                    // bytes, wave-uniform

  auto issue = [&](int buf, int k0) {
    gl16  (xg  + k0 + ao,  (char*)(&sA[buf][0]) + lbase);
    gl16nt(w1g + k0 + bo1, (char*)(&sB[buf][0]) + lbase);
    gl16nt(w1g + k0 + bo2, (char*)(&sB[buf][0]) + 8192 + lbase);
  };

  // Fragment read from swizzled fp32 tile + cvt to bf16x8 (k = kg*8..+7).
  auto frag = [&](const float* tb, int row) -> short8 {
    const float* p = tb + row * 32;
    int c0 = (((kg << 1) | 0) ^ (row & 7)) << 2;   // float offset of chunk
    int c1 = (((kg << 1) | 1) ^ (row & 7)) << 2;
    f32x4 lo = *(const f32x4*)(p + c0);
    f32x4 hi = *(const f32x4*)(p + c1);
    short8 r;
    r[0] = (short)f2bf(lo.x); r[1] = (short)f2bf(lo.y);
    r[2] = (short)f2bf(lo.z); r[3] = (short)f2bf(lo.w);
    r[4] = (short)f2bf(hi.x); r[5] = (short)f2bf(hi.y);
    r[6] = (short)f2bf(hi.z); r[7] = (short)f2bf(hi.w);
    return r;
  };

  const int NK = HD / 32;                          // 32 K-steps
  issue(0, 0);
  issue(1, 32);
  asm volatile("s_waitcnt vmcnt(3)" ::: "memory"); // tile0 landed
  __builtin_amdgcn_s_barrier();
  __builtin_amdgcn_sched_barrier(0);

  int cur = 0;
  for (int ks = 0; ks < NK; ++ks) {
    if (ks + 2 < NK) {
      int b2 = cur + 2; if (b2 >= 3) b2 -= 3;      // holds tile ks-1: free
      issue(b2, (ks + 2) * 32);
    }
    __builtin_amdgcn_sched_barrier(0);             // keep issues early

    short8 af[2], bfr[2];
    #pragma unroll
    for (int fm = 0; fm < 2; ++fm)
      af[fm] = frag(&sA[cur][0], wm * 32 + fm * 16 + lr);
    #pragma unroll
    for (int fn = 0; fn < 2; ++fn)
      bfr[fn] = frag(&sB[cur][0], wn * 32 + fn * 16 + lr);
    #pragma unroll
    for (int fm = 0; fm < 2; ++fm)
      #pragma unroll
      for (int fn = 0; fn < 2; ++fn)
        acc[fm][fn] = __builtin_amdgcn_mfma_f32_16x16x32_bf16(af[fm], bfr[fn], acc[fm][fn], 0, 0, 0);

    // Counted wait: tile ks+1 done, tile ks+2 stays in flight (T4).
    if (ks + 2 < NK) asm volatile("s_waitcnt vmcnt(3)" ::: "memory");
    else             asm volatile("s_waitcnt vmcnt(0)" ::: "memory");
    __builtin_amdgcn_s_barrier();
    __builtin_amdgcn_sched_barrier(0);
    cur += 1; if (cur >= 3) cur = 0;
  }

  // epilogue: gelu, cvt bf16, store h. C/D map: col=lane&15, row=(lane>>4)*4+j
  unsigned short* hp = hb + (size_t)e * CAPT * FD + nb * 128;
  #pragma unroll
  for (int fm = 0; fm < 2; ++fm)
    #pragma unroll
    for (int fn = 0; fn < 2; ++fn)
      #pragma unroll
      for (int j = 0; j < 4; ++j) {
        int m = wm * 32 + fm * 16 + (lane >> 4) * 4 + j;
        int f = wn * 32 + fn * 16 + lr;
        hp[(size_t)m * FD + f] = f2bf(gelu_t(acc[fm][fn][j]));
      }
}

#define A_SZ (64 * 128)
#define B_SZ (128 * 128)

// ---------------------------------------------------------------- pass 2 ---
// C2[64,1024] = h_e[64,2048](bf16) @ w2_e[2048,1024]  (NN: w2 transposed at
// stage time into LDS [n][k]). Unchanged from R6 (known-good).
__global__ __launch_bounds__(512, 4)
void moe_pass2(const unsigned short* __restrict__ hb, const float* __restrict__ w2,
               float* __restrict__ out) {
  __shared__ __align__(16) unsigned char sA[2 * A_SZ];
  __shared__ __align__(16) unsigned char sB[2 * B_SZ];
  const int bid = xcd_swz(blockIdx.x, NE * 8);
  const int e = bid >> 3, nb = bid & 7;
  const int t = threadIdx.x, lane = t & 63, wid = t >> 6;
  const int wm = wid >> 2, wn = wid & 3;
  const int lr = lane & 15, lkb = (lane >> 4) * 16;

  const unsigned short* hg = hb + (size_t)e * CAPT * FD;
  const float* w2g = w2 + (size_t)e * FD * HD + nb * 128;

  f32x4 acc[2][2] = {};

  const int ar = t >> 3, ac = t & 7;     // A: 512 units of 8 bf16, 1/thread
  const int bn = t & 127, bkg = t >> 7;  // B: lane owns col n, k-group of 16

  ushort8 rav;
  float rbv[16];
  auto loadT = [&](int f0) {
    rav = *(const ushort8*)(hg + (size_t)ar * FD + f0 + ac * 8);          // L2/L3-resident
    #pragma unroll
    for (int i = 0; i < 4; ++i)
      #pragma unroll
      for (int j = 0; j < 4; ++j)
        rbv[i * 4 + j] = __builtin_nontemporal_load(                       // single-use stream
            w2g + (size_t)(f0 + bkg * 16 + i * 4 + j) * HD + bn);
  };
  auto writeT = [&](unsigned char* a, unsigned char* b) {
    *(ushort8*)(a + swz(ar, ac * 16)) = rav;           // ds_write_b128
    #pragma unroll
    for (int i = 0; i < 4; ++i) {                      // transposed b64 writes
      uint2 p;
      p.x = (unsigned)f2bf(rbv[i * 4 + 0]) | ((unsigned)f2bf(rbv[i * 4 + 1]) << 16);
      p.y = (unsigned)f2bf(rbv[i * 4 + 2]) | ((unsigned)f2bf(rbv[i * 4 + 3]) << 16);
      *(uint2*)(b + swz(bn, (bkg * 16 + i * 4) * 2)) = p;
    }
  };

  const int NK = FD / 64;
  loadT(0);
  writeT(sA, sB);
  loadT(64);
  tile_barrier();

  int cur = 0;
  for (int ks = 0; ks < NK; ++ks) {
    unsigned char* cA = sA + cur * A_SZ;
    unsigned char* cB = sB + cur * B_SZ;
    if (ks + 1 < NK) writeT(sA + (cur ^ 1) * A_SZ, sB + (cur ^ 1) * B_SZ);
    if (ks + 2 < NK) loadT((ks + 2) * 64);

    short8 af[2][2], bf[2][2];
    #pragma unroll
    for (int fm = 0; fm < 2; ++fm)
      #pragma unroll
      for (int kk = 0; kk < 2; ++kk)
        af[fm][kk] = *(const short8*)(cA + swz(wm * 32 + fm * 16 + lr, kk * 64 + lkb));
    #pragma unroll
    for (int fn = 0; fn < 2; ++fn)
      #pragma unroll
      for (int kk = 0; kk < 2; ++kk)
        bf[fn][kk] = *(const short8*)(cB + swz(wn * 32 + fn * 16 + lr, kk * 64 + lkb));
    #pragma unroll
    for (int fm = 0; fm < 2; ++fm)
      #pragma unroll
      for (int fn = 0; fn < 2; ++fn) {
        acc[fm][fn] = __builtin_amdgcn_mfma_f32_16x16x32_bf16(af[fm][0], bf[fn][0], acc[fm][fn], 0, 0, 0);
        acc[fm][fn] = __builtin_amdgcn_mfma_f32_16x16x32_bf16(af[fm][1], bf[fn][1], acc[fm][fn], 0, 0, 0);
      }
    tile_barrier();
    cur ^= 1;
  }

  float* op = out + (size_t)e * CAPT * HD + nb * 128;
  #pragma unroll
  for (int fm = 0; fm < 2; ++fm)
    #pragma unroll
    for (int fn = 0; fn < 2; ++fn)
      #pragma unroll
      for (int j = 0; j < 4; ++j) {
        int m = wm * 32 + fm * 16 + (lane >> 4) * 4 + j;
        int n = wn * 32 + fn * 16 + lr;
        __builtin_nontemporal_store(acc[fm][fn][j], op + (size_t)m * HD + n);
      }
}

extern "C" void kernel_launch(void* const* d_in, const int* in_sizes, int n_in,
                              void* d_out, int out_size, void* d_ws, size_t ws_size,
                              hipStream_t stream) {
  const float* x  = (const float*)d_in[0];
  const float* w1 = (const float*)d_in[1];
  const float* w2 = (const float*)d_in[2];
  float* out = (float*)d_out;
  unsigned short* hb = (unsigned short*)d_ws;   // h: E*CAP*F bf16 = 16.78 MB
  (void)in_sizes; (void)n_in; (void)out_size; (void)ws_size;

  moe_pass1<<<dim3(NE * (FD / 128)), dim3(512), 0, stream>>>(x, w1, hb);
  moe_pass2<<<dim3(NE * (HD / 128)), dim3(512), 0, stream>>>(hb, w2, out);
}

// Round 10
// 204.770 us; speedup vs baseline: 1.1407x; 1.1407x over previous
//
#include <hip/hip_runtime.h>

// SparseMLP (grouped GEMM MoE): out = gelu_tanh(x @ w1^T) @ w2, per expert.
// E=64, CAP=64, H=1024, F=2048, fp32 in/out. HBM-bound: ~1.09 GB moved,
// roofline ~173us at the 6.29 TB/s copy ceiling (m13).
// R10: restore R6 two-kernel structure (R9 coop-launch failed silently).
// Pass 1 re-tiled to BN=64, BK=128: wave-level loads become 512B-contiguous
// per w1 row (vs 256B) and each DRAM page is visited 8x instead of 16x ->
// better page locality on the 512MB w1 stream. LDS 64KB dbuf, 2 blocks/CU,
// NK=8 (half the barriers). Pass 2 unchanged (known-good R6).
// nt loads on w/streams (R5), T1 XCD swizzle, T2 LDS XOR swizzle, T4 barriers.

typedef __attribute__((ext_vector_type(8))) short short8;    // 8 bf16 = 4 VGPR
typedef __attribute__((ext_vector_type(4))) float f32x4;     // MFMA acc / ld
typedef __attribute__((ext_vector_type(8))) unsigned short ushort8;

#define NE   64
#define CAPT 64
#define HD   1024
#define FD   2048

// fp32 -> bf16 round-to-nearest-even
__device__ __forceinline__ unsigned short f2bf(float f) {
  union { float f; unsigned u; } v; v.f = f;
  unsigned r = v.u + 0x7FFFu + ((v.u >> 16) & 1u);
  return (unsigned short)(r >> 16);
}

// gelu_tanh(v) = v * sigmoid(2*0.79788456*(v + 0.044715 v^3))  (exact rewrite)
__device__ __forceinline__ float gelu_t(float v) {
  float u = 1.5957691216057308f * (v + 0.044715f * v * v * v);
  return v / (1.0f + __expf(-u));
}

// XOR swizzle (T2) for a [rows][64]-bf16 tile (row stride 128B): pass 2.
__device__ __forceinline__ int swz(int row, int kbyte) {
  return row * 128 + (kbyte ^ ((row & 7) << 4));
}
// XOR swizzle for a [rows][128]-bf16 tile (row stride 256B): pass 1 (BK=128).
// XOR touches bits 4..6 only -> bijective within the row, 2-way max conflict.
__device__ __forceinline__ int swz2(int row, int kbyte) {
  return row * 256 + (kbyte ^ ((row & 7) << 4));
}

__device__ __forceinline__ void cvt_wr4(unsigned char* dst, f32x4 v) {
  uint2 p;
  p.x = (unsigned)f2bf(v.x) | ((unsigned)f2bf(v.y) << 16);
  p.y = (unsigned)f2bf(v.z) | ((unsigned)f2bf(v.w) << 16);
  *(uint2*)dst = p;   // ds_write_b64
}

// Raw barrier with LDS-only drain (T4): outstanding GLOBAL loads stay in
// flight across the barrier; register deps produce counted vmcnt waits.
__device__ __forceinline__ void tile_barrier() {
  asm volatile("s_waitcnt lgkmcnt(0)" ::: "memory");
  __builtin_amdgcn_s_barrier();
  __builtin_amdgcn_sched_barrier(0);
}

// Bijective XCD swizzle (T1): same-expert blocks share an L2.
__device__ __forceinline__ int xcd_swz(int bid, int grid) {
  return (bid & 7) * (grid >> 3) + (bid >> 3);
}

// ---------------------------------------------------------------- pass 1 ---
// C1[64,2048] = x_e[64,1024] @ w1_e[2048,1024]^T  (NT: both K-contiguous)
// grid = E*(F/64)=2048; tile BM=64 BN=64 BK=128; 8 waves (2x4), wave 32x16.
#define P1_TSZ (64 * 256)          // one [64][128]-bf16 buffer, bytes
__global__ __launch_bounds__(512, 4)
void moe_pass1(const float* __restrict__ x, const float* __restrict__ w1,
               unsigned short* __restrict__ hb) {
  __shared__ __align__(16) unsigned char sA[2 * P1_TSZ];   // 32 KB
  __shared__ __align__(16) unsigned char sB[2 * P1_TSZ];   // 32 KB
  const int bid = xcd_swz(blockIdx.x, NE * 32);
  const int e = bid >> 5, nb = bid & 31;
  const int t = threadIdx.x, lane = t & 63, wid = t >> 6;
  const int wm = wid >> 2, wn = wid & 3;
  const int lr = lane & 15, lk16 = (lane >> 4) * 16;

  const float* xg  = x  + (size_t)e * CAPT * HD;
  const float* w1g = w1 + ((size_t)e * FD + (size_t)nb * 64) * HD;

  f32x4 acc[2] = {};

  // Staging: tiles are 64 rows x 32 chunks(16B fp32). 2048 units, 4/thread.
  // u = t + i*512 -> row = u>>5 (t>>5 + i*16), chunk = u&31 (const per lane).
  // Per wave instruction: 2 rows x 512B contiguous.
  f32x4 ra[4], rb[4];
  auto loadT = [&](int k0) {
    #pragma unroll
    for (int i = 0; i < 4; ++i) {
      int u = t + i * 512;
      ra[i] = *(const f32x4*)(xg + (u >> 5) * HD + k0 + (u & 31) * 4);
    }
    #pragma unroll
    for (int i = 0; i < 4; ++i) {
      int u = t + i * 512;
      rb[i] = __builtin_nontemporal_load(                    // single-use stream
          (const f32x4*)(w1g + (u >> 5) * HD + k0 + (u & 31) * 4));
    }
  };
  auto writeT = [&](unsigned char* a, unsigned char* b) {
    #pragma unroll
    for (int i = 0; i < 4; ++i) {
      int u = t + i * 512;
      cvt_wr4(a + swz2(u >> 5, (u & 31) * 8), ra[i]);
    }
    #pragma unroll
    for (int i = 0; i < 4; ++i) {
      int u = t + i * 512;
      cvt_wr4(b + swz2(u >> 5, (u & 31) * 8), rb[i]);
    }
  };

  const int NK = HD / 128;                                   // 8 K-steps
  loadT(0);
  writeT(sA, sB);
  loadT(128);
  tile_barrier();

  int cur = 0;
  for (int ks = 0; ks < NK; ++ks) {
    unsigned char* cA = sA + cur * P1_TSZ;
    unsigned char* cB = sB + cur * P1_TSZ;
    if (ks + 1 < NK) writeT(sA + (cur ^ 1) * P1_TSZ, sB + (cur ^ 1) * P1_TSZ);
    if (ks + 2 < NK) loadT((ks + 2) * 128);

    #pragma unroll
    for (int kk = 0; kk < 4; ++kk) {                         // K=128 = 4x32
      short8 af0 = *(const short8*)(cA + swz2(wm * 32 + lr,      kk * 64 + lk16));
      short8 af1 = *(const short8*)(cA + swz2(wm * 32 + 16 + lr, kk * 64 + lk16));
      short8 bfr = *(const short8*)(cB + swz2(wn * 16 + lr,      kk * 64 + lk16));
      acc[0] = __builtin_amdgcn_mfma_f32_16x16x32_bf16(af0, bfr, acc[0], 0, 0, 0);
      acc[1] = __builtin_amdgcn_mfma_f32_16x16x32_bf16(af1, bfr, acc[1], 0, 0, 0);
    }
    tile_barrier();
    cur ^= 1;
  }

  // epilogue: gelu, cvt bf16, store h. C/D map: col=lane&15, row=(lane>>4)*4+j
  unsigned short* hp = hb + (size_t)e * CAPT * FD + nb * 64;
  #pragma unroll
  for (int fm = 0; fm < 2; ++fm)
    #pragma unroll
    for (int j = 0; j < 4; ++j) {
      int m = wm * 32 + fm * 16 + (lane >> 4) * 4 + j;
      int f = wn * 16 + lr;
      hp[(size_t)m * FD + f] = f2bf(gelu_t(acc[fm][j]));
    }
}

#define A_SZ (64 * 128)
#define B_SZ (128 * 128)

// ---------------------------------------------------------------- pass 2 ---
// C2[64,1024] = h_e[64,2048](bf16) @ w2_e[2048,1024]  (NN: w2 transposed at
// stage time into LDS [n][k]). Unchanged from R6 (known-good).
__global__ __launch_bounds__(512, 4)
void moe_pass2(const unsigned short* __restrict__ hb, const float* __restrict__ w2,
               float* __restrict__ out) {
  __shared__ __align__(16) unsigned char sA[2 * A_SZ];
  __shared__ __align__(16) unsigned char sB[2 * B_SZ];
  const int bid = xcd_swz(blockIdx.x, NE * 8);
  const int e = bid >> 3, nb = bid & 7;
  const int t = threadIdx.x, lane = t & 63, wid = t >> 6;
  const int wm = wid >> 2, wn = wid & 3;
  const int lr = lane & 15, lkb = (lane >> 4) * 16;

  const unsigned short* hg = hb + (size_t)e * CAPT * FD;
  const float* w2g = w2 + (size_t)e * FD * HD + nb * 128;

  f32x4 acc[2][2] = {};

  const int ar = t >> 3, ac = t & 7;     // A: 512 units of 8 bf16, 1/thread
  const int bn = t & 127, bkg = t >> 7;  // B: lane owns col n, k-group of 16

  ushort8 rav;
  float rbv[16];
  auto loadT = [&](int f0) {
    rav = *(const ushort8*)(hg + (size_t)ar * FD + f0 + ac * 8);          // L2/L3-warm
    #pragma unroll
    for (int i = 0; i < 4; ++i)
      #pragma unroll
      for (int j = 0; j < 4; ++j)
        rbv[i * 4 + j] = __builtin_nontemporal_load(                       // stream
            w2g + (size_t)(f0 + bkg * 16 + i * 4 + j) * HD + bn);
  };
  auto writeT = [&](unsigned char* a, unsigned char* b) {
    *(ushort8*)(a + swz(ar, ac * 16)) = rav;           // ds_write_b128
    #pragma unroll
    for (int i = 0; i < 4; ++i) {                      // transposed b64 writes
      uint2 p;
      p.x = (unsigned)f2bf(rbv[i * 4 + 0]) | ((unsigned)f2bf(rbv[i * 4 + 1]) << 16);
      p.y = (unsigned)f2bf(rbv[i * 4 + 2]) | ((unsigned)f2bf(rbv[i * 4 + 3]) << 16);
      *(uint2*)(b + swz(bn, (bkg * 16 + i * 4) * 2)) = p;
    }
  };

  const int NK = FD / 64;
  loadT(0);
  writeT(sA, sB);
  loadT(64);
  tile_barrier();

  int cur = 0;
  for (int ks = 0; ks < NK; ++ks) {
    unsigned char* cA = sA + cur * A_SZ;
    unsigned char* cB = sB + cur * B_SZ;
    if (ks + 1 < NK) writeT(sA + (cur ^ 1) * A_SZ, sB + (cur ^ 1) * B_SZ);
    if (ks + 2 < NK) loadT((ks + 2) * 64);

    short8 af[2][2], bf[2][2];
    #pragma unroll
    for (int fm = 0; fm < 2; ++fm)
      #pragma unroll
      for (int kk = 0; kk < 2; ++kk)
        af[fm][kk] = *(const short8*)(cA + swz(wm * 32 + fm * 16 + lr, kk * 64 + lkb));
    #pragma unroll
    for (int fn = 0; fn < 2; ++fn)
      #pragma unroll
      for (int kk = 0; kk < 2; ++kk)
        bf[fn][kk] = *(const short8*)(cB + swz(wn * 32 + fn * 16 + lr, kk * 64 + lkb));
    #pragma unroll
    for (int fm = 0; fm < 2; ++fm)
      #pragma unroll
      for (int fn = 0; fn < 2; ++fn) {
        acc[fm][fn] = __builtin_amdgcn_mfma_f32_16x16x32_bf16(af[fm][0], bf[fn][0], acc[fm][fn], 0, 0, 0);
        acc[fm][fn] = __builtin_amdgcn_mfma_f32_16x16x32_bf16(af[fm][1], bf[fn][1], acc[fm][fn], 0, 0, 0);
      }
    tile_barrier();
    cur ^= 1;
  }

  float* op = out + (size_t)e * CAPT * HD + nb * 128;
  #pragma unroll
  for (int fm = 0; fm < 2; ++fm)
    #pragma unroll
    for (int fn = 0; fn < 2; ++fn)
      #pragma unroll
      for (int j = 0; j < 4; ++j) {
        int m = wm * 32 + fm * 16 + (lane >> 4) * 4 + j;
        int n = wn * 32 + fn * 16 + lr;
        __builtin_nontemporal_store(acc[fm][fn][j], op + (size_t)m * HD + n);
      }
}

extern "C" void kernel_launch(void* const* d_in, const int* in_sizes, int n_in,
                              void* d_out, int out_size, void* d_ws, size_t ws_size,
                              hipStream_t stream) {
  const float* x  = (const float*)d_in[0];
  const float* w1 = (const float*)d_in[1];
  const float* w2 = (const float*)d_in[2];
  float* out = (float*)d_out;
  unsigned short* hb = (unsigned short*)d_ws;   // h: E*CAP*F bf16 = 16.78 MB
  (void)in_sizes; (void)n_in; (void)out_size; (void)ws_size;

  moe_pass1<<<dim3(NE * (FD / 64)), dim3(512), 0, stream>>>(x, w1, hb);
  moe_pass2<<<dim3(NE * (HD / 128)), dim3(512), 0, stream>>>(hb, w2, out);
}